// Round 9
// baseline (448.742 us; speedup 1.0000x reference)
//
#include <hip/hip_runtime.h>
#include <hip/hip_bf16.h>

using u16 = unsigned short;
using u32 = unsigned int;

#define NNODES 50000
#define NEDGE  200000
#define DEGCAP 64
#define NT     3125   // 50000 / 16 row-tiles

// ---------- bf16 helpers ----------
__device__ __forceinline__ float blo2f(u32 u) { u32 v = u << 16; float f; __builtin_memcpy(&f, &v, 4); return f; }
__device__ __forceinline__ float bhi2f(u32 u) { u32 v = u & 0xffff0000u; float f; __builtin_memcpy(&f, &v, 4); return f; }
__device__ __forceinline__ u16 f2b(float f) {
  __hip_bfloat16 h = __float2bfloat16(f);   // RNE
  u16 r; __builtin_memcpy(&r, &h, 2); return r;
}
__device__ __forceinline__ u32 pack2(float a, float b) {
  return (u32)f2b(a) | ((u32)f2b(b) << 16);
}
__device__ __forceinline__ float gelu_exact(float x) {
  return 0.5f * x * (1.f + erff(x * 0.70710678118654752f));
}

// ---------- async global->LDS (16B per lane), consecutive-lane coalesced ----------
__device__ __forceinline__ void gload16(const void* gp, void* lp) {
  __builtin_amdgcn_global_load_lds(
      (__attribute__((address_space(1))) u32*)(const_cast<void*>(gp)),
      (__attribute__((address_space(3))) u32*)lp, 16, 0, 0);
}

#define WAIT_VM(N) asm volatile("s_waitcnt vmcnt(" #N ")" ::: "memory")

typedef __bf16 bh8 __attribute__((ext_vector_type(8)));
typedef float f32x4 __attribute__((ext_vector_type(4)));

struct GArg { const u16* A; const u16* B; const float* bias; u16* C; };

// Block-cooperative bf16 stage (2 loads/wave): wave w deposits rows [w*4, w*4+4).
__device__ __forceinline__ void stage_blk_bf16(const u16* At, u16* buf, int wave, int lane) {
#pragma unroll
  for (int i = 0; i < 2; ++i) {
    const int row = wave * 4 + i * 2 + (lane >> 5);
    const int c   = (lane & 31) ^ (row & 7);
    gload16(At + (size_t)row * 256 + c * 8, buf + wave * 1024 + i * 512 + lane * 8);
  }
}

// Block-cooperative fp32 stage (4 loads/wave): 16B-chunk XOR (row&7) -> conflict-free.
__device__ __forceinline__ void stage_blk_f32(const float* At, float* buf, int wave, int lane) {
#pragma unroll
  for (int i = 0; i < 4; ++i) {
    const int row = wave * 4 + i;
    const int c   = lane ^ (row & 7);          // 16B chunk in [0,64)
    gload16(At + (size_t)row * 256 + c * 4, buf + row * 256 + lane * 4);
  }
}

// ---------- single-pass streaming GEMM (R4-exact best-known): C = A @ B^T + bias ----------
template <int MODE, bool F32A>
__launch_bounds__(256, 2)
__global__ void gemm_v10(GArg g0, GArg g1, GArg g2)
{
  GArg ga = (blockIdx.z == 0) ? g0 : ((blockIdx.z == 1) ? g1 : g2);
  const int tid  = threadIdx.x;
  const int lane = tid & 63;
  const int wave = tid >> 6;
  const int lr = lane & 15;
  const int lq = lane >> 4;
  const int colbase = wave * 64;                 // wave-private 64-col strip

  constexpr int TW = F32A ? 8192 : 4096;         // tile size in u16 units
  __shared__ alignas(16) u16 lds[3][TW];         // ring of 3 A-tiles
  __shared__ alignas(16) u16 pat[4][1152];       // per-wave epilogue patch, stride 72
  u16* wl = &pat[wave][0];

  bh8 B[4][8];
#pragma unroll
  for (int s = 0; s < 4; ++s) {
    const u16* bp = ga.B + (size_t)(colbase + s * 16 + lr) * 256 + lq * 8;
#pragma unroll
    for (int ks = 0; ks < 8; ++ks) B[s][ks] = *(const bh8*)(bp + ks * 32);
  }
  float bias[4];
#pragma unroll
  for (int s = 0; s < 4; ++s) bias[s] = ga.bias[colbase + s * 16 + lr];

  int foffL[8], foffH[8];
#pragma unroll
  for (int ks = 0; ks < 8; ++ks) {
    if (F32A) {
      foffL[ks] = lr * 256 + (((ks * 8 + lq * 2)     ^ (lr & 7)) << 2);
      foffH[ks] = lr * 256 + (((ks * 8 + lq * 2 + 1) ^ (lr & 7)) << 2);
    } else {
      foffL[ks] = lr * 256 + (((ks * 4 + lq) ^ (lr & 7)) * 8);
    }
  }

  const int t0 = blockIdx.x;
  const int ts = gridDim.x;

  if (F32A) stage_blk_f32((const float*)ga.A + (size_t)t0 * 4096, (float*)&lds[0][0], wave, lane);
  else      stage_blk_bf16(ga.A + (size_t)t0 * 4096, &lds[0][0], wave, lane);
  if (t0 + ts < NT) {
    if (F32A) stage_blk_f32((const float*)ga.A + (size_t)(t0 + ts) * 4096, (float*)&lds[1][0], wave, lane);
    else      stage_blk_bf16(ga.A + (size_t)(t0 + ts) * 4096, &lds[1][0], wave, lane);
  }

  int it = 0, rb = 0;
  for (int t = t0; t < NT; t += ts, ++it) {
    const bool p1 = (t + ts < NT), p2 = (t + 2 * ts < NT);
    if (p2) {
      const int rn = (rb + 2 >= 3) ? rb - 1 : rb + 2;
      if (F32A) stage_blk_f32((const float*)ga.A + (size_t)(t + 2 * ts) * 4096, (float*)&lds[rn][0], wave, lane);
      else      stage_blk_bf16(ga.A + (size_t)(t + 2 * ts) * 4096, &lds[rn][0], wave, lane);
    }
    if (!p1)            { WAIT_VM(0); }
    else if (!p2)       { if (F32A) { WAIT_VM(6); }  else { WAIT_VM(4); } }
    else if (it >= 2)   { if (F32A) { WAIT_VM(12); } else { WAIT_VM(8); } }
    else                { if (F32A) { WAIT_VM(8); }  else { WAIT_VM(4); } }
    __builtin_amdgcn_s_barrier();       // all waves' tile-t deposits visible

    bh8 ab[8];
    if (F32A) {
      const float* fbuf = (const float*)&lds[rb][0];
#pragma unroll
      for (int ks = 0; ks < 8; ++ks) {
        const f32x4 lo = *(const f32x4*)(fbuf + foffL[ks]);
        const f32x4 hi = *(const f32x4*)(fbuf + foffH[ks]);
#pragma unroll
        for (int j = 0; j < 4; ++j) { ab[ks][j] = (__bf16)lo[j]; ab[ks][j + 4] = (__bf16)hi[j]; }
      }
    } else {
      const u16* buf = &lds[rb][0];
#pragma unroll
      for (int ks = 0; ks < 8; ++ks) ab[ks] = *(const bh8*)(buf + foffL[ks]);
    }

    f32x4 acc[4];
#pragma unroll
    for (int s = 0; s < 4; ++s) acc[s] = (f32x4){0.f, 0.f, 0.f, 0.f};
#pragma unroll
    for (int ks = 0; ks < 8; ++ks) {
#pragma unroll
      for (int s = 0; s < 4; ++s)
        acc[s] = __builtin_amdgcn_mfma_f32_16x16x32_bf16(ab[ks], B[s][ks], acc[s], 0, 0, 0);
    }

#pragma unroll
    for (int s = 0; s < 4; ++s) {
#pragma unroll
      for (int r = 0; r < 4; ++r) {
        float v = acc[s][r] + bias[s];
        if (MODE == 0) v = fmaxf(v, 0.f);
        wl[(lq * 4 + r) * 72 + s * 16 + lr] = f2b(v);
      }
    }
#pragma unroll
    for (int j = 0; j < 2; ++j) {
      const int row = (lane >> 3) + j * 8;
      const int seg = lane & 7;
      const uint4 pv = *(const uint4*)(wl + row * 72 + seg * 8);   // lgkm wait auto
      *(uint4*)(ga.C + ((size_t)t * 16 + row) * 256 + colbase + seg * 8) = pv;
    }
    __builtin_amdgcn_s_barrier();       // all waves done reading lds[rb]
    rb = (rb + 1 == 3) ? 0 : rb + 1;
  }
}

// ---------- weight prep ----------
// y=0: lin0T  y=1: lin1T  y=2: qT  y=3: kfT(+bkf)  y=4: vfT(+bvf)
// y=5: Wpk[512][16] bf16 = [beta*(a_w1@out_w) ; (1-beta)*out_w] (k-major) + bfin[16]
// y=6: zero cnt
__global__ void prep_w_k(const float* __restrict__ lin_w, const float* __restrict__ q_w,
                         const float* __restrict__ a_w, const float* __restrict__ k_w,
                         const float* __restrict__ v_w, const float* __restrict__ k_b,
                         const float* __restrict__ v_b, const float* __restrict__ a_rel,
                         const float* __restrict__ m_rel, const float* __restrict__ out_w,
                         const float* __restrict__ a_b, const float* __restrict__ out_b,
                         const float* __restrict__ skipv,
                         u16* __restrict__ lin0T, u16* __restrict__ lin1T,
                         u16* __restrict__ qT,
                         u16* __restrict__ kfT, u16* __restrict__ vfT,
                         u16* __restrict__ Wpk, float* __restrict__ bfin,
                         float* __restrict__ bkf, float* __restrict__ bvf,
                         int* __restrict__ cnt)
{
  const int tid = blockIdx.x * 256 + threadIdx.x;  // 0..65535 ; out layout [n][k]
  const int nn = tid >> 8, kk = tid & 255;
  switch (blockIdx.y) {
    case 0: lin0T[tid] = f2b(lin_w[kk * 256 + nn]); break;
    case 1: lin1T[tid] = f2b(lin_w[65536 + kk * 256 + nn]); break;
    case 2: qT[tid] = f2b(q_w[65536 + kk * 256 + nn]); break;
    case 3: {
      const int h = nn >> 5, e = nn & 31;
      float s = 0.f;
      for (int d = 0; d < 32; ++d) s += k_w[kk * 256 + h * 32 + d] * a_rel[(h * 32 + d) * 32 + e];
      kfT[tid] = f2b(s);
      if (kk == 0) {
        float sb = 0.f;
        for (int d = 0; d < 32; ++d) sb += k_b[h * 32 + d] * a_rel[(h * 32 + d) * 32 + e];
        bkf[nn] = sb;
      }
      break;
    }
    case 4: {
      const int h = nn >> 5, e = nn & 31;
      float s = 0.f;
      for (int d = 0; d < 32; ++d) s += v_w[kk * 256 + h * 32 + d] * m_rel[(h * 32 + d) * 32 + e];
      vfT[tid] = f2b(s);
      if (kk == 0) {
        float sb = 0.f;
        for (int d = 0; d < 32; ++d) sb += v_b[h * 32 + d] * m_rel[(h * 32 + d) * 32 + e];
        bvf[nn] = sb;
      }
      break;
    }
    case 5: {
      const float beta = 1.f / (1.f + __expf(-skipv[1]));
      if (tid < 8192) {
        const int j = tid & 15;           // out col
        const int k = tid >> 4;           // 0..511
        float s;
        if (k < 256) {
          float acc = 0.f;
          for (int d = 0; d < 256; ++d)
            acc += a_w[65536 + k * 256 + d] * out_w[d * 16 + j];
          s = beta * acc;
        } else {
          s = (1.f - beta) * out_w[(k - 256) * 16 + j];
        }
        Wpk[k * 16 + j] = f2b(s);         // k-major: row k = 16 bf16 = 32 B
      }
      if (tid < 16) {
        float acc = 0.f;
        for (int c = 0; c < 256; ++c) acc += a_b[256 + c] * out_w[c * 16 + tid];
        bfin[tid] = beta * acc + out_b[tid];
      }
      break;
    }
    default:
      if (tid < NNODES) cnt[tid] = 0;
      break;
  }
}

// ---------- bucket-CSR build for edge type 0 (src type 0 -> dst type 1) ----------
__global__ void scatter_k(const int* __restrict__ ei, int* __restrict__ cnt, int* __restrict__ srcl) {
  const int e = blockIdx.x * 256 + threadIdx.x;
  if (e >= NEDGE) return;
  const int src = ei[e];          // edge_index[0][0][e]
  const int dst = ei[NEDGE + e];  // edge_index[0][1][e]
  if ((unsigned)dst >= NNODES || (unsigned)src >= NNODES) return;
  const int pos = atomicAdd(&cnt[dst], 1);
  if (pos < DEGCAP) srcl[(size_t)dst * DEGCAP + pos] = src;
}

// ---------- FUSED attention + aggregation + GELU + blend + out-projection ----------
// One wave per dst node (grid-stride). Phase 1 (as before): softmax-weighted
// aggregate -> r0..r3 per lane (lane owns dims off..off+3). Phase 2 (fused
// final): wave writes [o | h1] row (512 bf16, o in f32->bf16? NO: o stays via
// pack to LDS bf16x2 -- wait, o packed bf16 loses nothing vs old path which
// also stored bf16) to its PRIVATE 1 KB LDS strip; lane then owns c-chunk
// (lane&15)*32..+32 and j-group (lane>>4)*4..+4 of out = [o|h1] @ Wpk + bfin:
// 128 FMA from 32 loop-invariant W regs; 4-step shfl_xor (1,2,4,8) reduces the
// 16 c-chunks. No barriers (per-wave LDS + in-order DS + lgkmcnt waits).
// Replaces the separate final GEMM dispatch and the 51 MB gbuf round-trip.
__launch_bounds__(256, 3)
__global__ void edge_final_k(const u16* __restrict__ qb, const u16* __restrict__ krel,
                             const u16* __restrict__ vrel, const int* __restrict__ cnt,
                             const int* __restrict__ srcl, const float* __restrict__ prel,
                             const u16* __restrict__ h1, const u16* __restrict__ Wpk,
                             const float* __restrict__ bfin, float* __restrict__ out)
{
  const int lane = threadIdx.x & 63;
  const int wave = threadIdx.x >> 6;
  __shared__ alignas(8) u16 owl[4][512];      // per-wave [o | h1] row (1 KB each)
  u16* wlds = &owl[wave][0];

  // phase-1 lane mapping
  const int hh = lane >> 3;                   // head
  const int off = hh * 32 + (lane & 7) * 4;   // 4 dims per lane
  const float scale = prel[hh] * 0.17677669529663687f;   // p_rel[0][h]/sqrt(32)

  // phase-2 lane mapping + loop-invariant W registers (32 x uint2 = 64 VGPR)
  const int jg = lane >> 4;                   // j-group: cols jg*4..jg*4+3
  const int cbase = (lane & 15) * 32;         // c-chunk: rows cbase..cbase+31
  uint2 W[32];
#pragma unroll
  for (int i = 0; i < 32; ++i)
    W[i] = *(const uint2*)(Wpk + (size_t)(cbase + i) * 16 + jg * 4);
  float bj[4];
#pragma unroll
  for (int r = 0; r < 4; ++r) bj[r] = bfin[jg * 4 + r];

  const int wid0 = blockIdx.x * 4 + wave;
  const int wstride = gridDim.x * 4;

  for (int node = wid0; node < NNODES; node += wstride) {
    // ---- phase 1: attention aggregate (unchanged structure) ----
    const uint2 qv = *(const uint2*)(qb + (size_t)node * 256 + off);
    const float q0 = blo2f(qv.x) * scale, q1 = bhi2f(qv.x) * scale;
    const float q2 = blo2f(qv.y) * scale, q3 = bhi2f(qv.y) * scale;
    int dg = cnt[node]; if (dg > DEGCAP) dg = DEGCAP;
    const int mysrc = srcl[(size_t)node * DEGCAP + lane];

    float den = 0.f, a0 = 0.f, a1 = 0.f, a2 = 0.f, a3 = 0.f;
    uint2 kv = {0, 0}, vv = {0, 0};
    if (dg > 0) {
      const int s0 = __shfl(mysrc, 0);
      kv = *(const uint2*)(krel + (size_t)s0 * 256 + off);
      vv = *(const uint2*)(vrel + (size_t)s0 * 256 + off);
    }
    for (int i = 0; i < dg; ++i) {
      uint2 kn = kv, vn = vv;
      if (i + 1 < dg) {
        const int sn = __shfl(mysrc, i + 1);
        kn = *(const uint2*)(krel + (size_t)sn * 256 + off);
        vn = *(const uint2*)(vrel + (size_t)sn * 256 + off);
      }
      float p = q0 * blo2f(kv.x) + q1 * bhi2f(kv.x) + q2 * blo2f(kv.y) + q3 * bhi2f(kv.y);
      p += __shfl_xor(p, 1);
      p += __shfl_xor(p, 2);
      p += __shfl_xor(p, 4);           // 8-lane head-group reduce
      const float ex = __expf(p);      // |alpha| O(1): no max-subtraction
      den += ex;
      a0 += ex * blo2f(vv.x); a1 += ex * bhi2f(vv.x);
      a2 += ex * blo2f(vv.y); a3 += ex * bhi2f(vv.y);
      kv = kn; vv = vn;
    }
    float r0 = 0.f, r1 = 0.f, r2 = 0.f, r3 = 0.f;
    if (dg > 0) {
      const float inv = 1.f / den;
      r0 = gelu_exact(a0 * inv); r1 = gelu_exact(a1 * inv);
      r2 = gelu_exact(a2 * inv); r3 = gelu_exact(a3 * inv);
    }

    // ---- phase 2: [o | h1] -> per-wave LDS, then 512x16 dot ----
    const uint2 hv = *(const uint2*)(h1 + (size_t)node * 256 + off);
    uint2 ov; ov.x = pack2(r0, r1); ov.y = pack2(r2, r3);
    *(uint2*)(wlds + off)       = ov;
    *(uint2*)(wlds + 256 + off) = hv;
    asm volatile("s_waitcnt lgkmcnt(0)" ::: "memory");   // cross-lane LDS visible

    uint4 cv[4];
#pragma unroll
    for (int i = 0; i < 4; ++i) cv[i] = *(const uint4*)(wlds + cbase + i * 8);

    float p0 = 0.f, p1 = 0.f, p2 = 0.f, p3 = 0.f;
#pragma unroll
    for (int rr = 0; rr < 32; ++rr) {
      const u32 w32 = (rr & 4) ? ((rr & 2) ? cv[rr >> 3].w : cv[rr >> 3].z)
                               : ((rr & 2) ? cv[rr >> 3].y : cv[rr >> 3].x);
      const float oc = (rr & 1) ? bhi2f(w32) : blo2f(w32);
      const uint2 wv = W[rr];
      p0 += oc * blo2f(wv.x); p1 += oc * bhi2f(wv.x);
      p2 += oc * blo2f(wv.y); p3 += oc * bhi2f(wv.y);
    }
    // reduce the 16 c-chunks (lanes jg*16..jg*16+15)
#pragma unroll
    for (int m = 1; m <= 8; m <<= 1) {
      p0 += __shfl_xor(p0, m); p1 += __shfl_xor(p1, m);
      p2 += __shfl_xor(p2, m); p3 += __shfl_xor(p3, m);
    }
    if ((lane & 15) == 0) {
      float* op = out + (size_t)node * 16 + jg * 4;
      op[0] = p0 + bj[0]; op[1] = p1 + bj[1];
      op[2] = p2 + bj[2]; op[3] = p3 + bj[3];
    }
    asm volatile("s_waitcnt lgkmcnt(0)" ::: "memory");   // LDS reads done before next node's writes
  }
}

extern "C" void kernel_launch(void* const* d_in, const int* in_sizes, int n_in,
                              void* d_out, int out_size, void* d_ws, size_t ws_size,
                              hipStream_t stream)
{
  const float* x     = (const float*)d_in[0];
  const int*   ei    = (const int*)d_in[1];
  const float* lin_w = (const float*)d_in[2];
  const float* lin_b = (const float*)d_in[3];
  const float* k_w   = (const float*)d_in[4];
  const float* k_b   = (const float*)d_in[5];
  const float* q_w   = (const float*)d_in[6];
  const float* q_b   = (const float*)d_in[7];
  const float* v_w   = (const float*)d_in[8];
  const float* v_b   = (const float*)d_in[9];
  const float* a_w   = (const float*)d_in[10];
  const float* a_b   = (const float*)d_in[11];
  const float* skipv = (const float*)d_in[12];
  const float* a_rel = (const float*)d_in[13];
  const float* m_rel = (const float*)d_in[14];
  const float* p_rel = (const float*)d_in[15];
  const float* out_w = (const float*)d_in[16];
  const float* out_b = (const float*)d_in[17];
  char* ws = (char*)d_ws;

  // workspace layout (bytes):
  u16*  h0    = (u16*)(ws + 0);              // dead after mid GEMM
  u16*  h1    = (u16*)(ws + 25600000);       // alive till fused edge/final
  u16*  qb    = (u16*)(ws + 51200000);
  u16*  krel  = (u16*)(ws + 76800000);
  u16*  vrel  = (u16*)(ws + 102400000);
  char* W     = ws + 153600000;
  u16*  lin0T = (u16*)(W + 0);
  u16*  lin1T = (u16*)(W + 131072);
  u16*  qT    = (u16*)(W + 2 * 131072);
  u16*  kfT   = (u16*)(W + 3 * 131072);
  u16*  vfT   = (u16*)(W + 4 * 131072);
  u16*  Wpk   = (u16*)(W + 5 * 131072);              // 16 KB, [512][16] bf16
  float* bfin = (float*)(W + 5 * 131072 + 16384);    // 64 B
  float* bkf  = (float*)(W + 5 * 131072 + 17408);
  float* bvf  = (float*)(W + 5 * 131072 + 18432);
  int*  cnt   = (int*)(W + 5 * 131072 + 19456);
  int*  srcl  = (int*)(W + 5 * 131072 + 19456 + 200000);   // 12.8 MB

  prep_w_k<<<dim3(256, 7), 256, 0, stream>>>(lin_w, q_w, a_w, k_w, v_w, k_b, v_b,
                                             a_rel, m_rel, out_w, a_b, out_b, skipv,
                                             lin0T, lin1T, qT, kfT, vfT, Wpk, bfin,
                                             bkf, bvf, cnt);
  scatter_k<<<(NEDGE + 255) / 256, 256, 0, stream>>>(ei, cnt, srcl);

  {  // h[t] = relu(x[t] @ lin_w[t] + lin_b[t]) — fp32 A staged (R4-exact)
    GArg a0{(const u16*)x, lin0T, lin_b, h0};
    GArg a1{(const u16*)(x + (size_t)NNODES * 256), lin1T, lin_b + 256, h1};
    gemm_v10<0, true><<<dim3(256, 1, 2), 256, 0, stream>>>(a0, a1, a0);
  }
  {  // q1 = h1@q_w1+b ; krel = h0@(k_w0*a_rel0)+b' ; vrel = h0@(v_w0*m_rel0)+b'
    GArg a0{h1, qT, q_b + 256, qb};
    GArg a1{h0, kfT, bkf, krel};
    GArg a2{h0, vfT, bvf, vrel};
    gemm_v10<1, false><<<dim3(170, 1, 3), 256, 0, stream>>>(a0, a1, a2);
  }
  // fused: softmax-agg + GELU + skip-blend + out-projection (one dispatch)
  edge_final_k<<<1024, 256, 0, stream>>>(qb, krel, vrel, cnt, srcl, p_rel,
                                         h1, Wpk, bfin, (float*)d_out);
}

// Round 10
// 308.719 us; speedup vs baseline: 1.4536x; 1.4536x over previous
//
#include <hip/hip_runtime.h>
#include <hip/hip_bf16.h>

using u16 = unsigned short;
using u32 = unsigned int;

#define NNODES 50000
#define NEDGE  200000
#define DEGCAP 64
#define NT     3125   // 50000 / 16 row-tiles

// ---------- bf16 helpers ----------
__device__ __forceinline__ float blo2f(u32 u) { u32 v = u << 16; float f; __builtin_memcpy(&f, &v, 4); return f; }
__device__ __forceinline__ float bhi2f(u32 u) { u32 v = u & 0xffff0000u; float f; __builtin_memcpy(&f, &v, 4); return f; }
__device__ __forceinline__ u16 f2b(float f) {
  __hip_bfloat16 h = __float2bfloat16(f);   // RNE
  u16 r; __builtin_memcpy(&r, &h, 2); return r;
}
__device__ __forceinline__ float gelu_exact(float x) {
  return 0.5f * x * (1.f + erff(x * 0.70710678118654752f));
}

// ---------- async global->LDS (16B per lane), consecutive-lane coalesced ----------
__device__ __forceinline__ void gload16(const void* gp, void* lp) {
  __builtin_amdgcn_global_load_lds(
      (__attribute__((address_space(1))) u32*)(const_cast<void*>(gp)),
      (__attribute__((address_space(3))) u32*)lp, 16, 0, 0);
}
// Non-temporal variant (CPol NT = bit1 on gfx94x/gfx950): for streams with
// ZERO reuse (the fp32 x input). Keeps 102 MB of dead data out of L3 so the
// qkv/h intermediates stay resident for the edge/final consumers.
__device__ __forceinline__ void gload16_nt(const void* gp, void* lp) {
  __builtin_amdgcn_global_load_lds(
      (__attribute__((address_space(1))) u32*)(const_cast<void*>(gp)),
      (__attribute__((address_space(3))) u32*)lp, 16, 0, 2);
}

#define WAIT_VM(N) asm volatile("s_waitcnt vmcnt(" #N ")" ::: "memory")

typedef __bf16 bh8 __attribute__((ext_vector_type(8)));
typedef float f32x4 __attribute__((ext_vector_type(4)));

struct GArg { const u16* A; const u16* B; const float* bias; u16* C; };

// Block-cooperative bf16 stage (2 loads/wave): wave w deposits rows [w*4, w*4+4).
// Chunk XOR-swizzle (row&7) at 16B granularity -> conflict-free fragment reads.
__device__ __forceinline__ void stage_blk_bf16(const u16* At, u16* buf, int wave, int lane) {
#pragma unroll
  for (int i = 0; i < 2; ++i) {
    const int row = wave * 4 + i * 2 + (lane >> 5);
    const int c   = (lane & 31) ^ (row & 7);
    gload16(At + (size_t)row * 256 + c * 8, buf + wave * 1024 + i * 512 + lane * 8);
  }
}

// Block-cooperative fp32 stage (4 loads/wave), NON-TEMPORAL (x has zero reuse).
// 16B-chunk XOR (row&7): bank-start classes cover all 8 residues -> conflict-free.
__device__ __forceinline__ void stage_blk_f32(const float* At, float* buf, int wave, int lane) {
#pragma unroll
  for (int i = 0; i < 4; ++i) {
    const int row = wave * 4 + i;
    const int c   = lane ^ (row & 7);          // 16B chunk in [0,64)
    gload16_nt(At + (size_t)row * 256 + c * 4, buf + row * 256 + lane * 4);
  }
}

// ---------- single-pass streaming GEMM (R4-exact best-known): C = A @ B^T + bias ----------
// Ring of 3 LDS tile buffers, prefetch depth 2, counted vmcnt waits (never 0 in
// steady state). 2 blocks/CU ALWAYS: 256-reg unified VGPR/AGPR cap (the
// B[4][8]=128-reg strip must never face a 128-reg cap -> R3 spill lesson).
// F32A: A fp32, cvt to bf16 at fragment read (fuses the cvt_x pass).
// MODE 0: relu. MODE 1: bias only. bf16 out.
template <int MODE, bool F32A>
__launch_bounds__(256, 2)
__global__ void gemm_v10(GArg g0, GArg g1, GArg g2)
{
  GArg ga = (blockIdx.z == 0) ? g0 : ((blockIdx.z == 1) ? g1 : g2);
  const int tid  = threadIdx.x;
  const int lane = tid & 63;
  const int wave = tid >> 6;
  const int lr = lane & 15;
  const int lq = lane >> 4;
  const int colbase = wave * 64;                 // wave-private 64-col strip

  constexpr int TW = F32A ? 8192 : 4096;         // tile size in u16 units
  __shared__ alignas(16) u16 lds[3][TW];         // ring of 3 A-tiles
  __shared__ alignas(16) u16 pat[4][1152];       // per-wave epilogue patch, stride 72
  u16* wl = &pat[wave][0];

  // --- B: 4 strips x 8 k-chunks (64 cols x K=256) in registers/AGPRs ---
  bh8 B[4][8];
#pragma unroll
  for (int s = 0; s < 4; ++s) {
    const u16* bp = ga.B + (size_t)(colbase + s * 16 + lr) * 256 + lq * 8;
#pragma unroll
    for (int ks = 0; ks < 8; ++ks) B[s][ks] = *(const bh8*)(bp + ks * 32);
  }
  float bias[4];
#pragma unroll
  for (int s = 0; s < 4; ++s) bias[s] = ga.bias[colbase + s * 16 + lr];

  // fragment read offsets (swizzle-aware)
  int foffL[8], foffH[8];
#pragma unroll
  for (int ks = 0; ks < 8; ++ks) {
    if (F32A) {  // float index; lo/hi 16B chunks of the 8-float fragment
      foffL[ks] = lr * 256 + (((ks * 8 + lq * 2)     ^ (lr & 7)) << 2);
      foffH[ks] = lr * 256 + (((ks * 8 + lq * 2 + 1) ^ (lr & 7)) << 2);
    } else {     // u16 index of 8-bf16 fragment
      foffL[ks] = lr * 256 + (((ks * 4 + lq) ^ (lr & 7)) * 8);
    }
  }

  const int t0 = blockIdx.x;
  const int ts = gridDim.x;

  // prologue: stage t0 and t0+ts
  if (F32A) stage_blk_f32((const float*)ga.A + (size_t)t0 * 4096, (float*)&lds[0][0], wave, lane);
  else      stage_blk_bf16(ga.A + (size_t)t0 * 4096, &lds[0][0], wave, lane);
  if (t0 + ts < NT) {
    if (F32A) stage_blk_f32((const float*)ga.A + (size_t)(t0 + ts) * 4096, (float*)&lds[1][0], wave, lane);
    else      stage_blk_bf16(ga.A + (size_t)(t0 + ts) * 4096, &lds[1][0], wave, lane);
  }

  int it = 0, rb = 0;
  for (int t = t0; t < NT; t += ts, ++it) {
    const bool p1 = (t + ts < NT), p2 = (t + 2 * ts < NT);
    if (p2) {
      const int rn = (rb + 2 >= 3) ? rb - 1 : rb + 2;
      if (F32A) stage_blk_f32((const float*)ga.A + (size_t)(t + 2 * ts) * 4096, (float*)&lds[rn][0], wave, lane);
      else      stage_blk_bf16(ga.A + (size_t)(t + 2 * ts) * 4096, &lds[rn][0], wave, lane);
    }
    // exact younger-op counts (stage L loads + 2 stores per older iter):
    // f32 steady 2+4+2+4=12, bf16 2+2+2+2=8; conservative elsewhere.
    if (!p1)            { WAIT_VM(0); }
    else if (!p2)       { if (F32A) { WAIT_VM(6); }  else { WAIT_VM(4); } }
    else if (it >= 2)   { if (F32A) { WAIT_VM(12); } else { WAIT_VM(8); } }
    else                { if (F32A) { WAIT_VM(8); }  else { WAIT_VM(4); } }
    __builtin_amdgcn_s_barrier();       // all waves' tile-t deposits visible

    bh8 ab[8];
    if (F32A) {
      const float* fbuf = (const float*)&lds[rb][0];
#pragma unroll
      for (int ks = 0; ks < 8; ++ks) {
        const f32x4 lo = *(const f32x4*)(fbuf + foffL[ks]);
        const f32x4 hi = *(const f32x4*)(fbuf + foffH[ks]);
#pragma unroll
        for (int j = 0; j < 4; ++j) { ab[ks][j] = (__bf16)lo[j]; ab[ks][j + 4] = (__bf16)hi[j]; }
      }
    } else {
      const u16* buf = &lds[rb][0];
#pragma unroll
      for (int ks = 0; ks < 8; ++ks) ab[ks] = *(const bh8*)(buf + foffL[ks]);
    }

    f32x4 acc[4];
#pragma unroll
    for (int s = 0; s < 4; ++s) acc[s] = (f32x4){0.f, 0.f, 0.f, 0.f};
#pragma unroll
    for (int ks = 0; ks < 8; ++ks) {
#pragma unroll
      for (int s = 0; s < 4; ++s)
        acc[s] = __builtin_amdgcn_mfma_f32_16x16x32_bf16(ab[ks], B[s][ks], acc[s], 0, 0, 0);
    }

    // --- epilogue: acc -> per-wave LDS patch -> coalesced 64-col stores (2 insts) ---
#pragma unroll
    for (int s = 0; s < 4; ++s) {
#pragma unroll
      for (int r = 0; r < 4; ++r) {
        float v = acc[s][r] + bias[s];
        if (MODE == 0) v = fmaxf(v, 0.f);
        wl[(lq * 4 + r) * 72 + s * 16 + lr] = f2b(v);
      }
    }
#pragma unroll
    for (int j = 0; j < 2; ++j) {
      const int row = (lane >> 3) + j * 8;
      const int seg = lane & 7;
      const uint4 pv = *(const uint4*)(wl + row * 72 + seg * 8);   // lgkm wait auto
      *(uint4*)(ga.C + ((size_t)t * 16 + row) * 256 + colbase + seg * 8) = pv;
    }
    __builtin_amdgcn_s_barrier();       // all waves done reading lds[rb]
    rb = (rb + 1 == 3) ? 0 : rb + 1;
  }
}

// ---------- weight prep ----------
// y=0: lin0T  y=1: lin1T  y=2: qT  y=3: kfT(+bkf)  y=4: vfT(+bvf)
// y=5: WcT[16][512] = [beta*(a_w1@out_w) ; (1-beta)*out_w]^T + bfin[16]
// y=6: zero cnt
__global__ void prep_w_k(const float* __restrict__ lin_w, const float* __restrict__ q_w,
                         const float* __restrict__ a_w, const float* __restrict__ k_w,
                         const float* __restrict__ v_w, const float* __restrict__ k_b,
                         const float* __restrict__ v_b, const float* __restrict__ a_rel,
                         const float* __restrict__ m_rel, const float* __restrict__ out_w,
                         const float* __restrict__ a_b, const float* __restrict__ out_b,
                         const float* __restrict__ skipv,
                         u16* __restrict__ lin0T, u16* __restrict__ lin1T,
                         u16* __restrict__ qT,
                         u16* __restrict__ kfT, u16* __restrict__ vfT,
                         u16* __restrict__ WcT, float* __restrict__ bfin,
                         float* __restrict__ bkf, float* __restrict__ bvf,
                         int* __restrict__ cnt)
{
  const int tid = blockIdx.x * 256 + threadIdx.x;  // 0..65535 ; out layout [n][k]
  const int nn = tid >> 8, kk = tid & 255;
  switch (blockIdx.y) {
    case 0: lin0T[tid] = f2b(lin_w[kk * 256 + nn]); break;
    case 1: lin1T[tid] = f2b(lin_w[65536 + kk * 256 + nn]); break;
    case 2: qT[tid] = f2b(q_w[65536 + kk * 256 + nn]); break;
    case 3: {
      const int h = nn >> 5, e = nn & 31;
      float s = 0.f;
      for (int d = 0; d < 32; ++d) s += k_w[kk * 256 + h * 32 + d] * a_rel[(h * 32 + d) * 32 + e];
      kfT[tid] = f2b(s);
      if (kk == 0) {
        float sb = 0.f;
        for (int d = 0; d < 32; ++d) sb += k_b[h * 32 + d] * a_rel[(h * 32 + d) * 32 + e];
        bkf[nn] = sb;
      }
      break;
    }
    case 4: {
      const int h = nn >> 5, e = nn & 31;
      float s = 0.f;
      for (int d = 0; d < 32; ++d) s += v_w[kk * 256 + h * 32 + d] * m_rel[(h * 32 + d) * 32 + e];
      vfT[tid] = f2b(s);
      if (kk == 0) {
        float sb = 0.f;
        for (int d = 0; d < 32; ++d) sb += v_b[h * 32 + d] * m_rel[(h * 32 + d) * 32 + e];
        bvf[nn] = sb;
      }
      break;
    }
    case 5: {
      const float beta = 1.f / (1.f + __expf(-skipv[1]));
      if (tid < 8192) {
        const int j = tid & 15;           // out col
        const int k = tid >> 4;           // 0..511
        float s;
        if (k < 256) {
          float acc = 0.f;
          for (int d = 0; d < 256; ++d)
            acc += a_w[65536 + k * 256 + d] * out_w[d * 16 + j];
          s = beta * acc;
        } else {
          s = (1.f - beta) * out_w[(k - 256) * 16 + j];
        }
        WcT[j * 512 + k] = f2b(s);
      }
      if (tid < 16) {
        float acc = 0.f;
        for (int c = 0; c < 256; ++c) acc += a_b[256 + c] * out_w[c * 16 + tid];
        bfin[tid] = beta * acc + out_b[tid];
      }
      break;
    }
    default:
      if (tid < NNODES) cnt[tid] = 0;
      break;
  }
}

// ---------- bucket-CSR build for edge type 0 (src type 0 -> dst type 1) ----------
__global__ void scatter_k(const int* __restrict__ ei, int* __restrict__ cnt, int* __restrict__ srcl) {
  const int e = blockIdx.x * 256 + threadIdx.x;
  if (e >= NEDGE) return;
  const int src = ei[e];          // edge_index[0][0][e]
  const int dst = ei[NEDGE + e];  // edge_index[0][1][e]
  if ((unsigned)dst >= NNODES || (unsigned)src >= NNODES) return;
  const int pos = atomicAdd(&cnt[dst], 1);
  if (pos < DEGCAP) srcl[(size_t)dst * DEGCAP + pos] = src;
}

// ---------- fused attention softmax + aggregation + GELU; ONE WAVE PER NODE ----------
// (R9 lesson: this phase is gather-latency-bound and needs maximal TLP —
// 50000 independent waves, one node each. Do NOT grid-stride it.)
__global__ void edge_agg_k(const u16* __restrict__ qb, const u16* __restrict__ krel,
                           const u16* __restrict__ vrel, const int* __restrict__ cnt,
                           const int* __restrict__ srcl, const float* __restrict__ prel,
                           u16* __restrict__ g)
{
  const int node = (blockIdx.x * blockDim.x + threadIdx.x) >> 6;
  if (node >= NNODES) return;
  const int lane = threadIdx.x & 63;
  const int hh = lane >> 3;                 // head
  const int off = hh * 32 + (lane & 7) * 4; // 4 dims per lane
  const float scale = prel[hh] * 0.17677669529663687f;  // p_rel[0][h] / sqrt(32)
  const uint2 qv = *(const uint2*)(qb + (size_t)node * 256 + off);
  const float q0 = blo2f(qv.x) * scale, q1 = bhi2f(qv.x) * scale;
  const float q2 = blo2f(qv.y) * scale, q3 = bhi2f(qv.y) * scale;
  int dg = cnt[node]; if (dg > DEGCAP) dg = DEGCAP;
  const int mysrc = srcl[(size_t)node * DEGCAP + lane];   // whole list, coalesced

  float den = 0.f, a0 = 0.f, a1 = 0.f, a2 = 0.f, a3 = 0.f;
  uint2 kv = {0, 0}, vv = {0, 0};
  if (dg > 0) {
    const int s0 = __shfl(mysrc, 0);
    kv = *(const uint2*)(krel + (size_t)s0 * 256 + off);
    vv = *(const uint2*)(vrel + (size_t)s0 * 256 + off);
  }
  for (int i = 0; i < dg; ++i) {
    uint2 kn = kv, vn = vv;
    if (i + 1 < dg) {
      const int sn = __shfl(mysrc, i + 1);
      kn = *(const uint2*)(krel + (size_t)sn * 256 + off);
      vn = *(const uint2*)(vrel + (size_t)sn * 256 + off);
    }
    float p = q0 * blo2f(kv.x) + q1 * bhi2f(kv.x) + q2 * blo2f(kv.y) + q3 * bhi2f(kv.y);
    p += __shfl_xor(p, 1);
    p += __shfl_xor(p, 2);
    p += __shfl_xor(p, 4);           // 8-lane head-group reduce
    const float ex = __expf(p);      // no max-subtraction: |alpha| is O(1) here
    den += ex;
    a0 += ex * blo2f(vv.x); a1 += ex * bhi2f(vv.x);
    a2 += ex * blo2f(vv.y); a3 += ex * bhi2f(vv.y);
    kv = kn; vv = vn;
  }
  float r0 = 0.f, r1 = 0.f, r2 = 0.f, r3 = 0.f;
  if (dg > 0) {
    const float inv = 1.f / den;
    r0 = gelu_exact(a0 * inv); r1 = gelu_exact(a1 * inv);
    r2 = gelu_exact(a2 * inv); r3 = gelu_exact(a3 * inv);
  }
  uint2 gv;
  gv.x = (u32)f2b(r0) | ((u32)f2b(r1) << 16);
  gv.y = (u32)f2b(r2) | ((u32)f2b(r3) << 16);
  *(uint2*)(g + (size_t)node * 256 + off) = gv;
}

// ---------- fused blend + out GEMM, block-cooperative K-split (R4-exact) ----------
// out[50000,16] = [gelu_agg | h1] (50000x512) @ WcT^T + bfin.
__launch_bounds__(256, 3)
__global__ void final_v10(const u16* __restrict__ g, const u16* __restrict__ h1,
                          const u16* __restrict__ WcT, const float* __restrict__ bfin,
                          float* __restrict__ out)
{
  const int tid = threadIdx.x;
  const int lane = tid & 63;
  const int wave = tid >> 6;
  const int lr = lane & 15;
  const int lq = lane >> 4;

  __shared__ alignas(16) u16 lds[3][8192];   // ring: [quarter w][16 rows][128 cols bf16]
  __shared__ float red[4][256];              // partial sums

  bh8 B[4];
  {
    const u16* bp = WcT + (size_t)lr * 512 + wave * 128 + lq * 8;
#pragma unroll
    for (int ks = 0; ks < 4; ++ks) B[ks] = *(const bh8*)(bp + ks * 32);
  }
  const float bv = bfin[tid & 15];

  int foff[4];
#pragma unroll
  for (int ks = 0; ks < 4; ++ks)
    foff[ks] = wave * 2048 + lr * 128 + (((ks * 4 + lq) ^ (lr & 7)) * 8);  // u16 units

  const u16* srcq = (wave < 2) ? g + wave * 128 : h1 + (wave - 2) * 128;

  const int t0 = blockIdx.x;
  const int ts = gridDim.x;

#define FSTAGE(T, RB)                                                          \
  {                                                                            \
    _Pragma("unroll")                                                          \
    for (int i = 0; i < 4; ++i) {                                              \
      const int row = i * 4 + (lane >> 4);                                     \
      const int c   = (lane & 15) ^ (row & 7);                                 \
      gload16(srcq + (size_t)(T) * 4096 + row * 256 + c * 8,                   \
              &lds[RB][wave * 2048 + i * 512 + lane * 8]);                     \
    }                                                                          \
  }

  FSTAGE(t0, 0);
  if (t0 + ts < NT) FSTAGE(t0 + ts, 1);

  int it = 0, rb = 0;
  for (int t = t0; t < NT; t += ts, ++it) {
    const bool p1 = (t + ts < NT), p2 = (t + 2 * ts < NT);
    if (p2) {
      const int rn = (rb + 2 >= 3) ? rb - 1 : rb + 2;
      FSTAGE(t + 2 * ts, rn);
    }
    if (!p1)          { WAIT_VM(0); }
    else if (!p2)     { WAIT_VM(4); }
    else if (it >= 2) { WAIT_VM(10); }
    else              { WAIT_VM(8); }
    __builtin_amdgcn_s_barrier();

    f32x4 acc = {0.f, 0.f, 0.f, 0.f};
    const u16* buf = &lds[rb][0];
#pragma unroll
    for (int ks = 0; ks < 4; ++ks)
      acc = __builtin_amdgcn_mfma_f32_16x16x32_bf16(*(const bh8*)(buf + foff[ks]), B[ks], acc, 0, 0, 0);

#pragma unroll
    for (int r = 0; r < 4; ++r) red[wave][(lq * 4 + r) * 16 + lr] = acc[r];
    asm volatile("s_waitcnt lgkmcnt(0)" ::: "memory");   // partials visible pre-barrier
    __builtin_amdgcn_s_barrier();

    const float s = red[0][tid] + red[1][tid] + red[2][tid] + red[3][tid] + bv;
    out[(size_t)t * 256 + tid] = s;                      // 1 coalesced store inst
    __builtin_amdgcn_s_barrier();                        // red/lds reusable
    rb = (rb + 1 == 3) ? 0 : rb + 1;
  }
#undef FSTAGE
}

extern "C" void kernel_launch(void* const* d_in, const int* in_sizes, int n_in,
                              void* d_out, int out_size, void* d_ws, size_t ws_size,
                              hipStream_t stream)
{
  const float* x     = (const float*)d_in[0];
  const int*   ei    = (const int*)d_in[1];
  const float* lin_w = (const float*)d_in[2];
  const float* lin_b = (const float*)d_in[3];
  const float* k_w   = (const float*)d_in[4];
  const float* k_b   = (const float*)d_in[5];
  const float* q_w   = (const float*)d_in[6];
  const float* q_b   = (const float*)d_in[7];
  const float* v_w   = (const float*)d_in[8];
  const float* v_b   = (const float*)d_in[9];
  const float* a_w   = (const float*)d_in[10];
  const float* a_b   = (const float*)d_in[11];
  const float* skipv = (const float*)d_in[12];
  const float* a_rel = (const float*)d_in[13];
  const float* m_rel = (const float*)d_in[14];
  const float* p_rel = (const float*)d_in[15];
  const float* out_w = (const float*)d_in[16];
  const float* out_b = (const float*)d_in[17];
  char* ws = (char*)d_ws;

  // workspace layout (bytes):
  u16*  h0    = (u16*)(ws + 0);              // dead after mid GEMM
  u16*  h1    = (u16*)(ws + 25600000);       // alive till final
  u16*  qb    = (u16*)(ws + 51200000);       // dead after edge_agg
  u16*  krel  = (u16*)(ws + 76800000);       // dead after edge_agg
  u16*  vrel  = (u16*)(ws + 102400000);      // dead after edge_agg
  u16*  gbuf  = (u16*)(ws + 128000000);      // dead after final
  char* W     = ws + 153600000;
  u16*  lin0T = (u16*)(W + 0);
  u16*  lin1T = (u16*)(W + 131072);
  u16*  qT    = (u16*)(W + 2 * 131072);
  u16*  kfT   = (u16*)(W + 3 * 131072);
  u16*  vfT   = (u16*)(W + 4 * 131072);
  u16*  WcT   = (u16*)(W + 5 * 131072);              // 16 KB
  float* bfin = (float*)(W + 5 * 131072 + 16384);    // 64 B
  float* bkf  = (float*)(W + 5 * 131072 + 17408);
  float* bvf  = (float*)(W + 5 * 131072 + 18432);
  int*  cnt   = (int*)(W + 5 * 131072 + 19456);
  int*  srcl  = (int*)(W + 5 * 131072 + 19456 + 200000);   // 12.8 MB

  prep_w_k<<<dim3(256, 7), 256, 0, stream>>>(lin_w, q_w, a_w, k_w, v_w, k_b, v_b,
                                             a_rel, m_rel, out_w, a_b, out_b, skipv,
                                             lin0T, lin1T, qT, kfT, vfT, WcT, bfin,
                                             bkf, bvf, cnt);
  scatter_k<<<(NEDGE + 255) / 256, 256, 0, stream>>>(ei, cnt, srcl);

  {  // h[t] = relu(x[t] @ lin_w[t] + lin_b[t]) — fp32 A staged NT (zero-reuse stream)
    GArg a0{(const u16*)x, lin0T, lin_b, h0};
    GArg a1{(const u16*)(x + (size_t)NNODES * 256), lin1T, lin_b + 256, h1};
    gemm_v10<0, true><<<dim3(256, 1, 2), 256, 0, stream>>>(a0, a1, a0);
  }
  {  // q1 = h1@q_w1+b ; krel = h0@(k_w0*a_rel0)+b' ; vrel = h0@(v_w0*m_rel0)+b'
    GArg a0{h1, qT, q_b + 256, qb};
    GArg a1{h0, kfT, bkf, krel};
    GArg a2{h0, vfT, bvf, vrel};
    gemm_v10<1, false><<<dim3(170, 1, 3), 256, 0, stream>>>(a0, a1, a2);
  }
  edge_agg_k<<<12500, 256, 0, stream>>>(qb, krel, vrel, cnt, srcl, p_rel, gbuf);
  // out = beta*(gelu(agg)@a_w1+a_b1)@out_w + (1-beta)*h1@out_w + out_b  (folded)
  final_v10<<<768, 256, 0, stream>>>(gbuf, h1, WcT, bfin, (float*)d_out);
}